// Round 10
// baseline (199.895 us; speedup 1.0000x reference)
//
#include <hip/hip_runtime.h>

// CTC batch cost (keras ctc_batch_cost semantics), forward only.
// B=512, T=512, C=128 (blank=127), L=32, S=65.
//
// Round-10: r9 fwd/bwd-split + COALESCED WARM-AHEAD STREAM.
// Evidence r3-r9: kernel ~60us invariant to LDS/VALU/depth/code-size; the
// invariant across all = per-CU totals of scattered cold-miss requests.
// Kernel HBM rate never exceeded ~1.1 TB/s (~27 lines in flight/CU at
// ~900cy), while coalesced streaming sustains 6.3 TB/s chip-wide (m13).
// Fix: each wave warms its OWN rows ~8 groups ahead with coalesced
// stride-16B dword loads (16 full lines per instr, line-granular fill);
// the recurrence's scattered loadQ then hits L2/L3 (~200-450cy) instead of
// cold HBM. Warming is a pure perf hint (no sync needed; 134MB < 256MB L3,
// nothing evicts during the kernel). Warm ring: 16 regs, consumed 8 groups
// later into a dead wsum (kept alive by an asm sink) purely for liveness;
// warm issued AFTER loadQ per group so counted Q-waits never drain
// younger warms. Compute path byte-identical to r9 (absmax must stay 4.0).

#define EPSF 1e-7f

constexpr int C_  = 128;
constexpr int L_  = 32;
constexpr int PFG = 4;     // register prefetch depth for scattered loadQ

// lane j -> value of lane j-1; lane 0 -> 0.  (DPP wave_shr:1, bound_ctrl=0-fill)
__device__ __forceinline__ float wshr1(float x) {
    return __int_as_float(
        __builtin_amdgcn_mov_dpp(__float_as_int(x), 0x138, 0xf, 0xf, true));
}

// Exponent of strided wave max of v (lanes 3,7,...,63). Positive floats:
// int-max of bit patterns == bit pattern of float max; only exponent used.
// 27 = biased exponent of the 1e-30 dead-sample guard (self-corrects).
__device__ __forceinline__ int sample_eb(float v) {
    int mb = __builtin_amdgcn_readlane(__float_as_int(v), 3);
#pragma unroll
    for (int i = 1; i < 16; ++i) {
        const int t = __builtin_amdgcn_readlane(__float_as_int(v), 4 * i + 3);
        mb = (t > mb) ? t : mb;
    }
    const int eb = (int)((unsigned)mb >> 23);
    return (eb > 27) ? eb : 27;
}

__launch_bounds__(128)
__global__ void ctc_loss_kernel(const int* __restrict__ y_true,
                                const float* __restrict__ y_pred,
                                float* __restrict__ out) {
    __shared__ float shR[65];   // reversed wave's alpha' (its states 0..64)
    __shared__ int   shE;       // reversed wave's exponent total

    const int b    = blockIdx.x;
    const int tid  = threadIdx.x;
    const int lane = tid & 63;
    const int w    = tid >> 6;   // 0 = forward, 1 = reversed

    const float* bb  = y_pred + (size_t)b * 512 * C_;
    const int*   lbl = y_true + b * L_;

    // Per-lane class & skip flag. Forward: state = lane over ext(labels).
    // Reversed: state = lane over ext(reversed labels); skip'(v)=skip(66-v).
    int   cls0 = C_ - 1;
    float sg0  = 0.f;
    if (w == 0) {
        if (lane & 1) cls0 = lbl[(lane - 1) >> 1];
        if ((lane & 1) && lane >= 3) {
            const int li = (lane - 1) >> 1;
            if (lbl[li] != lbl[li - 1]) sg0 = 1.f;
        }
    } else {
        if (lane & 1) cls0 = lbl[31 - ((lane - 1) >> 1)];
        if ((lane & 1) && lane >= 3) {
            const int li = (lane - 1) >> 1;
            if (lbl[31 - li] != lbl[32 - li]) sg0 = 1.f;
        }
    }

    // Recursion-time t (0..255) -> original row: fwd t, rev 511-t.
    auto rowp = [&](int t) {
        const int orig = w ? (511 - t) : t;
        return bb + (size_t)orig * C_ + cls0;
    };
    const int rs = w ? -C_ : C_;   // element stride for +1 recursion row

    // t=0 init (prob domain): states 0,1 = q(row0')[cls]+eps, rest 0.
    float a       = (lane < 2) ? (rowp(0)[0] + EPSF) : 0.f;
    float a64     = 0.f;   // state-64 sink, meaningful on lane 63 only
    int   e_total = 0;     // accumulated log2 scale (exact integer)

    auto loadQ = [&](float (&Pk)[4], int g) {
        const float* r = rowp(1 + 4 * g);
        Pk[0] = r[0]; Pk[1] = r[rs]; Pk[2] = r[2 * rs]; Pk[3] = r[3 * rs];
    };

    // Coalesced warm of group g's 4 rows (2 KB): two stride-16B dword loads,
    // 16 full 64B lines each — line-granular L2/L3 fill of the whole rows.
    auto warm = [&](float& A, float& B, int g) {
        const int r0 = w ? (507 - 4 * g) : (1 + 4 * g);
        const float* p = bb + (size_t)r0 * C_ + lane * 4;
        A = p[0];       // rows r0, r0+1
        B = p[256];     // rows r0+2, r0+3
    };

    // Composed 4-row update, column-0 collapsed form (r5-proven).
    auto group4 = [&](const float (&P)[4]) {
        float x = a, z = a64;
#pragma unroll
        for (int r = 0; r < 4; ++r) {
            const float q  = P[r] + EPSF;
            const float qs = wshr1(q);      // blank-column value at lane 63
            const float x1 = wshr1(x);
            const float x2 = wshr1(x1);
            z = (z + x) * qs;               // state-64 sink (pre-update x)
            x = (x + x1 + sg0 * x2) * q;
        }
        a = x; a64 = z;
    };

    // Exact pow2 rescale from a previously-sampled exponent (r5-proven).
    auto scale = [&](int eb) {
        e_total += eb - 127;
        const float inv = __uint_as_float((unsigned)(254 - eb) << 23);  // 2^-e
        a *= inv; a64 *= inv;
    };

    // Warm prologue: groups 0..7 (coalesced; issued before anything else).
    float Wa[8], Wb[8];
    float wsum = 0.f;
#pragma unroll
    for (int k = 0; k < 8; ++k) warm(Wa[k], Wb[k], k);

    // Scattered prefetch prologue: groups 0..3.
    float Q[PFG][4];
#pragma unroll
    for (int k = 0; k < PFG; ++k) loadQ(Q[k], k);
    int ebp = sample_eb(a);

    // Main loop: groups 0..55, rolled 7 x 8. Per group g:
    //   consume warm ring slot g&7 (liveness; wait subsumed by Q-wait),
    //   compute group g, rescale, resample,
    //   scattered-load group g+4, warm group g+8 (clamped 62).
#pragma clang loop unroll(disable)
    for (int gq = 0; gq < 7; ++gq) {
#pragma unroll
        for (int k = 0; k < 8; ++k) {
            const int g = gq * 8 + k;
            wsum += Wa[k] + Wb[k];
            group4(Q[k & 3]);
            scale(ebp);
            ebp = sample_eb(a);
            loadQ(Q[k & 3], g + 4);
            int gw = g + 8; if (gw > 62) gw = 62;
            warm(Wa[k], Wb[k], gw);
        }
    }

    // Tail-row loads (recursion rows 253..255), issued before the epilogue.
    float qo[3];
#pragma unroll
    for (int r = 0; r < 3; ++r) qo[r] = rowp(253 + r)[0];

    // Epilogue groups 56..62.
#pragma unroll
    for (int j = 0; j < 7; ++j) {
        wsum += Wa[j] + Wb[j];
        group4(Q[j & 3]);
        scale(ebp);
        if (j < 6) ebp = sample_eb(a);
        if (j < 3) loadQ(Q[j & 3], 60 + j);
    }
    wsum += Wa[7] + Wb[7];   // consume last ring slot

    // Recursion rows 253..255, single steps (no rescale).
#pragma unroll
    for (int r = 0; r < 3; ++r) {
        const float p1 = wshr1(a);
        const float p2 = wshr1(p1);
        const float qb = wshr1(qo[r]);
        const float an = (a + p1 + sg0 * p2) * (qo[r] + EPSF);
        a64 = (a64 + a) * (qb + EPSF);
        a = an;
    }
    // Both waves now hold alpha after 256 rows (fwd: rows 0..255;
    // rev: rows 511..256 of the reversed problem).

    if (w == 1) {
        shR[lane] = a;                 // alpha'[state lane], states 0..63
        if (lane == 63) shR[64] = a64; // alpha'[64]
        if (lane == 0)  shE = e_total;
    }
    __syncthreads();

    if (w == 0) {
        // Pre-emission predecessor sum for target state s2 = lane.
        const float a1 = wshr1(a);
        const float a2 = wshr1(a1);
        const float abar = a + a1 + sg0 * a2;
        // Junction dot-product in DOUBLE: halves are independently
        // normalized; matched terms can be ~2^-136 (f32 flushes -> inf bug).
        double p = (double)abar * (double)shR[64 - lane];
        if (lane == 63) p += (double)(a64 + a) * (double)shR[0];
#pragma unroll
        for (int m = 1; m < 64; m <<= 1) p += __shfl(p, lane ^ m);
        if (lane == 0) {
            if (p < 1e-300) p = 1e-300;            // guard (never hit in range)
            const unsigned long long bt = __double_as_longlong(p);
            const int k = (int)((bt >> 52) & 0x7FFULL) - 1023;
            const double mant = __longlong_as_double(
                (bt & 0x000FFFFFFFFFFFFFULL) | 0x3FF0000000000000ULL);  // [1,2)
            out[b] = -(__logf((float)mant) +
                       (float)(e_total + shE + k) * 0.6931471805599453f);
        }
    }

    // Keep the warm ring alive to kernel end (prevents DCE of warm loads;
    // value is meaningless). All loads complete before endpgm via the
    // compiler's counted waits on this use.
    asm volatile("" :: "v"(wsum));
}

extern "C" void kernel_launch(void* const* d_in, const int* in_sizes, int n_in,
                              void* d_out, int out_size, void* d_ws, size_t ws_size,
                              hipStream_t stream) {
    const int*   y_true = (const int*)d_in[0];
    const float* y_pred = (const float*)d_in[1];
    float*       out    = (float*)d_out;

    const int B = out_size;   // output is [B,1]
    ctc_loss_kernel<<<B, 128, 0, stream>>>(y_true, y_pred, out);
}